// Round 10
// baseline (198.689 us; speedup 1.0000x reference)
//
#include <hip/hip_runtime.h>
#include <hip/hip_bf16.h>

#define T_DIM 64
#define B_DIM 4
#define INP_D 768
#define Q_D   384
#define E_D   384
#define DFF_D 1536
#define NTOK  256

typedef short bf16x8 __attribute__((ext_vector_type(8)));
typedef float f32x4  __attribute__((ext_vector_type(4)));

__device__ __forceinline__ float sigf(float x)  { return 1.0f / (1.0f + __expf(-x)); }
__device__ __forceinline__ float elu1f(float x) { return x > 0.0f ? x + 1.0f : __expf(x); }

__device__ __forceinline__ short f2b(float x) {
  union { __hip_bfloat16 b; short s; } u;
  u.b = __float2bfloat16(x);
  return u.s;
}
__device__ __forceinline__ bf16x8 cvt8(float4 a, float4 b) {
  bf16x8 r;
  r[0] = f2b(a.x); r[1] = f2b(a.y); r[2] = f2b(a.z); r[3] = f2b(a.w);
  r[4] = f2b(b.x); r[5] = f2b(b.y); r[6] = f2b(b.z); r[7] = f2b(b.w);
  return r;
}

// ---------------------------------------------------------------------------
// Workspace: f32 region [0,1376256) then bf16 region (short offsets below).
// Total 4,571,136 f32 = 18.3 MB (fits proven 22.4 MB).
// ---------------------------------------------------------------------------
#define WS_FORGET 0
#define WS_QUERY  98304
#define WS_KEYV   196608
#define WS_VALUE  294912
#define WS_PATT   393216      // [8][256][384] f32
#define WS_HPRE   1179648     // [256][768] f32
#define WS_BF     1376256     // bf16 region start (f32 offset)
// bf16-element offsets:
#define PB_INP   0            // [256][768]
#define PB_MIXED 196608       // [256][768]
#define PB_ATTN  393216       // [256][384]
#define PB_H     491520       // [256][768]
#define PB_G     688128       // [256][1536]
#define PK_MIX   1081344      // packed 768x384
#define PK_LAYER 1376256      // packed 768x1536
#define PK_PROJ  2555904      // packed 384x768
#define PK_W1    2850816      // packed 768x1536
#define PK_W2    4030464      // packed 768x1536
#define PK_W3    5210112      // packed 1536x768 (end 6389760)

// ---------------------------------------------------------------------------
// Conversion dispatch: 2784 blocks.
//   0..2591: weights -> packed MFMA-B fragments (proven R8 layout)
//   2592..2687: inp   -> inp_bf   (row-major bf16)
//   2688..2783: mixed -> mixed_bf (computed once, row-major bf16)
// ---------------------------------------------------------------------------
__global__ __launch_bounds__(256) void k_conv(const float* __restrict__ inp,
                                              const float* __restrict__ is_first,
                                              const float* __restrict__ init_inp,
                                              const float* __restrict__ mu,
                                              const float* __restrict__ mixW,
                                              const float* __restrict__ layerW,
                                              const float* __restrict__ projW,
                                              const float* __restrict__ W1,
                                              const float* __restrict__ W2,
                                              const float* __restrict__ W3,
                                              short* __restrict__ wsb) {
  const int blk = blockIdx.x;
  const int tid = threadIdx.x;
  if (blk >= 2592) {
    if (blk < 2688) {      // inp -> bf16
      const int idx = (blk - 2592) * 2048 + tid * 8;
      float4 a = *(const float4*)&inp[idx], b = *(const float4*)&inp[idx + 4];
      *(bf16x8*)&wsb[PB_INP + idx] = cvt8(a, b);
    } else {               // mixed -> bf16
      const int idx = (blk - 2688) * 2048 + tid * 8;
      const int c = idx % INP_D, tok = idx / INP_D;
      const int t = tok >> 2, b = tok & 3;
      const float fr = (t == 0) ? 1.0f : is_first[tok];
      const float* lastp = (fr > 0.5f) ? &init_inp[b * INP_D + c] : &inp[idx - 4 * INP_D];
      float4 x0 = *(const float4*)&inp[idx], x1 = *(const float4*)&inp[idx + 4];
      float4 l0 = *(const float4*)&lastp[0], l1 = *(const float4*)&lastp[4];
      float4 m0 = *(const float4*)&mu[c],    m1 = *(const float4*)&mu[c + 4];
      float4 r0, r1;
      r0.x = m0.x * x0.x + (1.0f - m0.x) * l0.x;
      r0.y = m0.y * x0.y + (1.0f - m0.y) * l0.y;
      r0.z = m0.z * x0.z + (1.0f - m0.z) * l0.z;
      r0.w = m0.w * x0.w + (1.0f - m0.w) * l0.w;
      r1.x = m1.x * x1.x + (1.0f - m1.x) * l1.x;
      r1.y = m1.y * x1.y + (1.0f - m1.y) * l1.y;
      r1.z = m1.z * x1.z + (1.0f - m1.z) * l1.z;
      r1.w = m1.w * x1.w + (1.0f - m1.w) * l1.w;
      *(bf16x8*)&wsb[PB_MIXED + idx] = cvt8(r0, r1);
    }
    return;
  }
  const float* src; short* dst; int N, kb, nb64;
  if (blk < 144)        { src = mixW;   dst = wsb + PK_MIX;   N = 384;  int r = blk;        kb = r / 6;  nb64 = r % 6; }
  else if (blk < 720)   { src = layerW; dst = wsb + PK_LAYER; N = 1536; int r = blk - 144;  kb = r / 24; nb64 = r % 24; }
  else if (blk < 864)   { src = projW;  dst = wsb + PK_PROJ;  N = 768;  int r = blk - 720;  kb = r / 12; nb64 = r % 12; }
  else if (blk < 1440)  { src = W1;     dst = wsb + PK_W1;    N = 1536; int r = blk - 864;  kb = r / 24; nb64 = r % 24; }
  else if (blk < 2016)  { src = W2;     dst = wsb + PK_W2;    N = 1536; int r = blk - 1440; kb = r / 24; nb64 = r % 24; }
  else                  { src = W3;     dst = wsb + PK_W3;    N = 768;  int r = blk - 2016; kb = r / 12; nb64 = r % 12; }

  __shared__ float lds[32][68];
  {
    const int r = tid >> 3, c8 = (tid & 7) * 8;
    const float* p = &src[(size_t)(kb * 32 + r) * N + nb64 * 64 + c8];
    *(float4*)&lds[r][c8]     = *(const float4*)p;
    *(float4*)&lds[r][c8 + 4] = *(const float4*)(p + 4);
  }
  __syncthreads();
  {
    const int nb = tid >> 6, lane = tid & 63, g = lane >> 4, c = lane & 15;
    unsigned int w[4];
#pragma unroll
    for (int jj = 0; jj < 4; ++jj) {
      unsigned short lo = (unsigned short)f2b(lds[g * 8 + jj * 2][nb * 16 + c]);
      unsigned short hi = (unsigned short)f2b(lds[g * 8 + jj * 2 + 1][nb * 16 + c]);
      w[jj] = (unsigned int)lo | ((unsigned int)hi << 16);
    }
    const int N16 = N >> 4;
    size_t o = ((size_t)kb * N16 + (nb64 * 4 + nb)) * 512 + lane * 8;
    uint4 pk; pk.x = w[0]; pk.y = w[1]; pk.z = w[2]; pk.w = w[3];
    *(uint4*)&dst[o] = pk;
  }
}

// ---------------------------------------------------------------------------
// MFMA core (SUBT 16-col subtiles). A loads are direct bf16 dwordx4.
// ---------------------------------------------------------------------------
template<int KSTEPS, int SUBT, bool DUAL, int ASTRIDE>
__device__ __forceinline__ void mm_core(const short* __restrict__ Arow, int kg,
                                        const short* __restrict__ B1, int bn1, int N16a,
                                        const short* __restrict__ B2, int bn2, int N16b,
                                        int lane, f32x4* acc1, f32x4* acc2) {
  bf16x8 a_c = *(const bf16x8*)&Arow[kg];
  bf16x8 b1c[SUBT], b2c[SUBT];
#pragma unroll
  for (int s = 0; s < SUBT; ++s)
    b1c[s] = *(const bf16x8*)&B1[((size_t)(bn1 + s)) * 512 + lane * 8];
  if constexpr (DUAL) {
#pragma unroll
    for (int s = 0; s < SUBT; ++s)
      b2c[s] = *(const bf16x8*)&B2[((size_t)(bn2 + s)) * 512 + lane * 8];
  }
#pragma unroll 2
  for (int kb = 0; kb < KSTEPS; ++kb) {
    bf16x8 a_n = a_c;
    bf16x8 b1n[SUBT], b2n[SUBT];
    if (kb + 1 < KSTEPS) {
      a_n = *(const bf16x8*)&Arow[(kb + 1) * 32 + kg];
#pragma unroll
      for (int s = 0; s < SUBT; ++s)
        b1n[s] = *(const bf16x8*)&B1[((size_t)(kb + 1) * N16a + bn1 + s) * 512 + lane * 8];
      if constexpr (DUAL) {
#pragma unroll
        for (int s = 0; s < SUBT; ++s)
          b2n[s] = *(const bf16x8*)&B2[((size_t)(kb + 1) * N16b + bn2 + s) * 512 + lane * 8];
      }
    }
#pragma unroll
    for (int s = 0; s < SUBT; ++s)
      acc1[s] = __builtin_amdgcn_mfma_f32_16x16x32_bf16(a_c, b1c[s], acc1[s], 0, 0, 0);
    if constexpr (DUAL) {
#pragma unroll
      for (int s = 0; s < SUBT; ++s)
        acc2[s] = __builtin_amdgcn_mfma_f32_16x16x32_bf16(a_c, b2c[s], acc2[s], 0, 0, 0);
    }
    a_c = a_n;
#pragma unroll
    for (int s = 0; s < SUBT; ++s) b1c[s] = b1n[s];
    if constexpr (DUAL) {
#pragma unroll
      for (int s = 0; s < SUBT; ++s) b2c[s] = b2n[s];
    }
  }
}

#define WAVE_SETUP  const int tid = threadIdx.x, w = tid >> 6, l = tid & 63; \
                    const int m0 = blockIdx.x * 64; \
                    const int rowA = m0 + w * 16 + (l & 15); \
                    const int kg = (l >> 4) * 8; (void)kg;

// ---------------------------------------------------------------------------
// Merged fg + parts. Grid (4, 48), 32-col wave tiles. A = mixed_bf / inp_bf.
// ---------------------------------------------------------------------------
__global__ __launch_bounds__(256) void k_qkvfg(const short* __restrict__ inp_bf,
                                               const short* __restrict__ mixed_bf,
                                               const short* __restrict__ Mixp,
                                               const short* __restrict__ Lp,
                                               const float* __restrict__ drops,
                                               float* __restrict__ forget,
                                               float* __restrict__ query,
                                               float* __restrict__ keyv,
                                               float* __restrict__ value) {
  WAVE_SETUP
  const int y = blockIdx.y;
  if (y < 12) {
    const int n0 = y * 32, bn = y * 2;
    const short* Arow = &mixed_bf[(size_t)rowA * INP_D];
    f32x4 acc[2] = {(f32x4){0.f,0.f,0.f,0.f}, (f32x4){0.f,0.f,0.f,0.f}};
    mm_core<24, 2, false, INP_D>(Arow, kg, Mixp, bn, 24, nullptr, 0, 0, l, acc, nullptr);
#pragma unroll
    for (int i = 0; i < 4; ++i) {
      const int row = m0 + w * 16 + ((l >> 4) << 2) + i;
      const float d = drops[row];
#pragma unroll
      for (int s = 0; s < 2; ++s) {
        const int col = n0 + s * 16 + (l & 15);
        forget[(size_t)row * Q_D + col] = (sigf(acc[s][i]) - 1.0f) * d + 1.0f;
      }
    }
    return;
  }
  const short* Arow = &inp_bf[(size_t)rowA * INP_D];
  if (y < 36) {
    const bool isq = (y < 24);
    const int yy = isq ? y - 12 : y - 24;
    float* dst = isq ? query : keyv;
    const int bn = (isq ? 0 : 24) + yy * 2;
    f32x4 acc[2] = {(f32x4){0.f,0.f,0.f,0.f}, (f32x4){0.f,0.f,0.f,0.f}};
    mm_core<24, 2, false, INP_D>(Arow, kg, Lp, bn, 96, nullptr, 0, 0, l, acc, nullptr);
#pragma unroll
    for (int i = 0; i < 4; ++i) {
      const int row = m0 + w * 16 + ((l >> 4) << 2) + i;
      const float d = drops[row];
#pragma unroll
      for (int s = 0; s < 2; ++s) {
        const int col = yy * 32 + s * 16 + (l & 15);
        dst[(size_t)row * Q_D + col] = elu1f(acc[s][i] * d);
      }
    }
  } else {
    const int q = y - 36;
    const int bn_r = 48 + q * 2, bn_v = 72 + q * 2;
    f32x4 a1[2] = {(f32x4){0.f,0.f,0.f,0.f}, (f32x4){0.f,0.f,0.f,0.f}};
    f32x4 a2[2] = {(f32x4){0.f,0.f,0.f,0.f}, (f32x4){0.f,0.f,0.f,0.f}};
    mm_core<24, 2, true, INP_D>(Arow, kg, Lp, bn_r, 96, Lp, bn_v, 96, l, a1, a2);
#pragma unroll
    for (int i = 0; i < 4; ++i) {
      const int row = m0 + w * 16 + ((l >> 4) << 2) + i;
      const float d = drops[row];
#pragma unroll
      for (int s = 0; s < 2; ++s) {
        const int col = q * 32 + s * 16 + (l & 15);
        value[(size_t)row * E_D + col] = sigf(a1[s][i] * d) * (a2[s][i] * d);
      }
    }
  }
}

// ---------------------------------------------------------------------------
// proj: hpre = attn_bf @ proj_W + inp. Grid (4, 24).
// ---------------------------------------------------------------------------
__global__ __launch_bounds__(256) void k_proj(const short* __restrict__ attn_bf,
                                              const short* __restrict__ Bp,
                                              const float* __restrict__ inp,
                                              float* __restrict__ hpre) {
  WAVE_SETUP
  const int n0 = blockIdx.y * 32, bn = blockIdx.y * 2;
  const short* Arow = &attn_bf[(size_t)rowA * E_D];
  f32x4 acc[2] = {(f32x4){0.f,0.f,0.f,0.f}, (f32x4){0.f,0.f,0.f,0.f}};
  mm_core<12, 2, false, E_D>(Arow, kg, Bp, bn, 48, nullptr, 0, 0, l, acc, nullptr);
#pragma unroll
  for (int i = 0; i < 4; ++i) {
    const int row = m0 + w * 16 + ((l >> 4) << 2) + i;
#pragma unroll
    for (int s = 0; s < 2; ++s) {
      const int col = n0 + s * 16 + (l & 15);
      hpre[(size_t)row * INP_D + col] = acc[s][i] + inp[(size_t)row * INP_D + col];
    }
  }
}

// ---------------------------------------------------------------------------
// FFN dual: g_bf = bf16(silu(h@W1) * (h@W2)). Grid (4, 48).
// ---------------------------------------------------------------------------
__global__ __launch_bounds__(256) void k_ffn(const short* __restrict__ h_bf,
                                             const short* __restrict__ W1p,
                                             const short* __restrict__ W2p,
                                             short* __restrict__ g_bf) {
  WAVE_SETUP
  const int n0 = blockIdx.y * 32, bn = blockIdx.y * 2;
  const short* Arow = &h_bf[(size_t)rowA * INP_D];
  f32x4 a1[2] = {(f32x4){0.f,0.f,0.f,0.f}, (f32x4){0.f,0.f,0.f,0.f}};
  f32x4 a2[2] = {(f32x4){0.f,0.f,0.f,0.f}, (f32x4){0.f,0.f,0.f,0.f}};
  mm_core<24, 2, true, INP_D>(Arow, kg, W1p, bn, 96, W2p, bn, 96, l, a1, a2);
#pragma unroll
  for (int i = 0; i < 4; ++i) {
    const int row = m0 + w * 16 + ((l >> 4) << 2) + i;
#pragma unroll
    for (int s = 0; s < 2; ++s) {
      const int col = n0 + s * 16 + (l & 15);
      const float v1 = a1[s][i], v2 = a2[s][i];
      g_bf[(size_t)row * DFF_D + col] = f2b(v1 * sigf(v1) * v2);
    }
  }
}

// ---------------------------------------------------------------------------
// out = g_bf @ W3. Grid (4, 24).
// ---------------------------------------------------------------------------
__global__ __launch_bounds__(256) void k_out(const short* __restrict__ g_bf,
                                             const short* __restrict__ Bp,
                                             float* __restrict__ out) {
  WAVE_SETUP
  const int n0 = blockIdx.y * 32, bn = blockIdx.y * 2;
  const short* Arow = &g_bf[(size_t)rowA * DFF_D];
  f32x4 acc[2] = {(f32x4){0.f,0.f,0.f,0.f}, (f32x4){0.f,0.f,0.f,0.f}};
  mm_core<48, 2, false, DFF_D>(Arow, kg, Bp, bn, 48, nullptr, 0, 0, l, acc, nullptr);
#pragma unroll
  for (int i = 0; i < 4; ++i) {
    const int row = m0 + w * 16 + ((l >> 4) << 2) + i;
#pragma unroll
    for (int s = 0; s < 2; ++s) {
      const int col = n0 + s * 16 + (l & 15);
      out[(size_t)row * INP_D + col] = acc[s][i];
    }
  }
}

// ---------------------------------------------------------------------------
// Segmented scan: double-buffered stg/pacc, ONE __syncthreads per t-step.
// Grid (6, 8, 4), 256 threads, 12 states/thread.
// ---------------------------------------------------------------------------
__global__ __launch_bounds__(256) void k_scan(const float* __restrict__ forget,
                                              const float* __restrict__ query,
                                              const float* __restrict__ keyv,
                                              const float* __restrict__ value,
                                              const float* __restrict__ is_first,
                                              const float* __restrict__ init_state,
                                              float* __restrict__ patt) {
  __shared__ float stg[2][144];
  __shared__ float pacc[2][256];
  const int tid = threadIdx.x;
  const int e  = blockIdx.x * 64 + (tid & 63);
  const int qg = tid >> 6;
  const int qc = blockIdx.y;
  const int b  = blockIdx.z;
  const int q0 = qc * 48 + qg * 12;

  float s[12], ini[12];
#pragma unroll
  for (int j = 0; j < 12; ++j) {
    ini[j] = init_state[((size_t)b * Q_D + q0 + j) * E_D + e];
    s[j]   = ini[j];
  }

  auto stageld = [&](int tok) -> float {   // valid for tid < 144
    const int which = tid / 48, o = tid % 48;
    const float* src = which == 0 ? forget : (which == 1 ? keyv : query);
    return src[(size_t)tok * Q_D + qc * 48 + o];
  };

  // prologue: stage t=0 into stg[0]
  float v_c, if_c;
  if (tid < 144) stg[0][tid] = stageld(b);
  v_c  = value[(size_t)b * E_D + e];
  if_c = 0.0f;
  __syncthreads();

  for (int t = 0; t < T_DIM; ++t) {
    const int tok = t * B_DIM + b;
    const int cur = t & 1;
    // prefetch t+1 into registers
    float stage_n = 0.0f, v_n = 0.0f, if_n = 0.0f;
    if (t + 1 < T_DIM) {
      const int tok1 = tok + B_DIM;
      if (tid < 144) stage_n = stageld(tok1);
      v_n  = value[(size_t)tok1 * E_D + e];
      if_n = is_first[tok1];
    }
    if (if_c > 0.5f) {
#pragma unroll
      for (int j = 0; j < 12; ++j) s[j] = ini[j];
    }
    const float4* f4 = (const float4*)&stg[cur][qg * 12];
    const float4* k4 = (const float4*)&stg[cur][48 + qg * 12];
    const float4* q4 = (const float4*)&stg[cur][96 + qg * 12];
    float p = 0.0f;
#pragma unroll
    for (int jj = 0; jj < 3; ++jj) {
      const float4 fv = f4[jj], kv = k4[jj], qv = q4[jj];
#pragma unroll
      for (int j2 = 0; j2 < 4; ++j2) {
        const int sj = jj * 4 + j2;
        s[sj] = fmaf((&fv.x)[j2], s[sj], (&kv.x)[j2] * v_c);
        p     = fmaf((&qv.x)[j2], s[sj], p);
      }
    }
    pacc[cur][tid] = p;
    if (t + 1 < T_DIM && tid < 144) stg[cur ^ 1][tid] = stage_n;  // safe: last read pre-sync(t-1)
    __syncthreads();
    if (tid < 64) {
      float r = pacc[cur][tid] + pacc[cur][tid + 64] + pacc[cur][tid + 128] + pacc[cur][tid + 192];
      patt[((size_t)qc * NTOK + tok) * E_D + blockIdx.x * 64 + tid] = r;
    }
    v_c  = v_n;
    if_c = if_n;
  }
}

// sum 8 scan slabs + RMS norm -> attn_bf (bf16)
__global__ __launch_bounds__(128) void ep_rms(const float* __restrict__ patt,
                                              const float* __restrict__ rms_w,
                                              short* __restrict__ attn_bf) {
  const int tok = blockIdx.x, tid = threadIdx.x;
  float x[3], ss = 0.0f;
#pragma unroll
  for (int i = 0; i < 3; ++i) {
    const int e = i * 128 + tid;
    float a = 0.0f;
#pragma unroll
    for (int qc = 0; qc < 8; ++qc) a += patt[((size_t)qc * NTOK + tok) * E_D + e];
    x[i] = a;
    ss = fmaf(a, a, ss);
  }
#pragma unroll
  for (int off = 32; off; off >>= 1) ss += __shfl_down(ss, off, 64);
  __shared__ float r[2];
  const int wid = tid >> 6, lane = tid & 63;
  if (lane == 0) r[wid] = ss;
  __syncthreads();
  ss = r[0] + r[1];
  const float sc = rsqrtf(ss * (1.0f / E_D) + 1e-6f);
#pragma unroll
  for (int i = 0; i < 3; ++i) {
    const int e = i * 128 + tid;
    attn_bf[(size_t)tok * E_D + e] = f2b(x[i] * sc * rms_w[e]);
  }
}

// LayerNorm over hpre -> h_bf (bf16)
__global__ __launch_bounds__(256) void ep_ln(const float* __restrict__ hpre,
                                             const float* __restrict__ ln_w,
                                             const float* __restrict__ ln_b,
                                             short* __restrict__ h_bf) {
  const int tok = blockIdx.x, tid = threadIdx.x;
  float x[3], s1 = 0.0f, s2 = 0.0f;
#pragma unroll
  for (int i = 0; i < 3; ++i) {
    x[i] = hpre[(size_t)tok * INP_D + i * 256 + tid];
    s1 += x[i];
    s2 = fmaf(x[i], x[i], s2);
  }
#pragma unroll
  for (int off = 32; off; off >>= 1) {
    s1 += __shfl_down(s1, off, 64);
    s2 += __shfl_down(s2, off, 64);
  }
  __shared__ float r1[4], r2[4];
  const int wid = tid >> 6, lane = tid & 63;
  if (lane == 0) { r1[wid] = s1; r2[wid] = s2; }
  __syncthreads();
  s1 = r1[0] + r1[1] + r1[2] + r1[3];
  s2 = r2[0] + r2[1] + r2[2] + r2[3];
  const float mean = s1 * (1.0f / INP_D);
  const float var  = s2 * (1.0f / INP_D) - mean * mean;
  const float sc   = rsqrtf(var + 1e-5f);
#pragma unroll
  for (int i = 0; i < 3; ++i) {
    const int c = i * 256 + tid;
    h_bf[(size_t)tok * INP_D + c] = f2b((x[i] - mean) * sc * ln_w[c] + ln_b[c]);
  }
}

extern "C" void kernel_launch(void* const* d_in, const int* in_sizes, int n_in,
                              void* d_out, int out_size, void* d_ws, size_t ws_size,
                              hipStream_t stream) {
  (void)in_sizes; (void)n_in; (void)out_size; (void)ws_size;
  const float* inp        = (const float*)d_in[0];
  const float* is_first   = (const float*)d_in[1];
  const float* drops      = (const float*)d_in[2];
  const float* init_inp   = (const float*)d_in[3];
  const float* init_state = (const float*)d_in[4];
  const float* mix_mu     = (const float*)d_in[5];
  const float* mix_W      = (const float*)d_in[6];
  const float* layer_W    = (const float*)d_in[7];
  const float* proj_W     = (const float*)d_in[8];
  const float* rms_w      = (const float*)d_in[9];
  const float* ln_w       = (const float*)d_in[10];
  const float* ln_b       = (const float*)d_in[11];
  const float* W1         = (const float*)d_in[12];
  const float* W2         = (const float*)d_in[13];
  const float* W3         = (const float*)d_in[14];
  float* out = (float*)d_out;
  float* ws  = (float*)d_ws;
  short* wsb = (short*)(ws + WS_BF);

  float* forget = ws + WS_FORGET;
  float* query  = ws + WS_QUERY;
  float* keyv   = ws + WS_KEYV;
  float* value  = ws + WS_VALUE;
  float* patt   = ws + WS_PATT;
  float* hpre   = ws + WS_HPRE;

  k_conv<<<2784, 256, 0, stream>>>(inp, is_first, init_inp, mix_mu,
                                   mix_W, layer_W, proj_W, W1, W2, W3, wsb);
  k_qkvfg<<<dim3(4, 48), 256, 0, stream>>>(wsb + PB_INP, wsb + PB_MIXED,
                                           wsb + PK_MIX, wsb + PK_LAYER, drops,
                                           forget, query, keyv, value);
  k_scan<<<dim3(6, 8, 4), 256, 0, stream>>>(forget, query, keyv, value,
                                            is_first, init_state, patt);
  ep_rms<<<NTOK, 128, 0, stream>>>(patt, rms_w, wsb + PB_ATTN);
  k_proj<<<dim3(4, 24), 256, 0, stream>>>(wsb + PB_ATTN, wsb + PK_PROJ, inp, hpre);
  ep_ln<<<NTOK, 256, 0, stream>>>(hpre, ln_w, ln_b, wsb + PB_H);
  k_ffn<<<dim3(4, 48), 256, 0, stream>>>(wsb + PB_H, wsb + PK_W1, wsb + PK_W2, wsb + PB_G);
  k_out<<<dim3(4, 24), 256, 0, stream>>>(wsb + PB_G, wsb + PK_W3, out);
}

// Round 11
// 170.486 us; speedup vs baseline: 1.1654x; 1.1654x over previous
//
#include <hip/hip_runtime.h>
#include <hip/hip_bf16.h>

#define T_DIM 64
#define B_DIM 4
#define INP_D 768
#define Q_D   384
#define E_D   384
#define DFF_D 1536
#define NTOK  256

typedef short bf16x8 __attribute__((ext_vector_type(8)));
typedef float f32x4  __attribute__((ext_vector_type(4)));

__device__ __forceinline__ float sigf(float x)  { return 1.0f / (1.0f + __expf(-x)); }
__device__ __forceinline__ float elu1f(float x) { return x > 0.0f ? x + 1.0f : __expf(x); }

__device__ __forceinline__ short f2b(float x) {
  union { __hip_bfloat16 b; short s; } u;
  u.b = __float2bfloat16(x);
  return u.s;
}
__device__ __forceinline__ bf16x8 cvt8(float4 a, float4 b) {
  bf16x8 r;
  r[0] = f2b(a.x); r[1] = f2b(a.y); r[2] = f2b(a.z); r[3] = f2b(a.w);
  r[4] = f2b(b.x); r[5] = f2b(b.y); r[6] = f2b(b.z); r[7] = f2b(b.w);
  return r;
}

// ---------------------------------------------------------------------------
// Workspace: f32 region [0,1376256) then bf16 region (short offsets below).
// ---------------------------------------------------------------------------
#define WS_FORGET 0
#define WS_QUERY  98304
#define WS_KEYV   196608
#define WS_VALUE  294912
#define WS_PATT   393216      // [8][256][384] f32
#define WS_HPRE   1179648     // [256][768] f32
#define WS_BF     1376256     // bf16 region start (f32 offset)
// bf16-element offsets:
#define PB_INP   0            // [256][768]
#define PB_MIXED 196608       // [256][768]
#define PB_ATTN  393216       // [256][384]
#define PB_H     491520       // [256][768]
#define PB_G     688128       // [256][1536]
#define PK_MIX   1081344      // packed 768x384
#define PK_LAYER 1376256      // packed 768x1536
#define PK_PROJ  2555904      // packed 384x768
#define PK_W1    2850816      // packed 768x1536
#define PK_W2    4030464      // packed 768x1536
#define PK_W3    5210112      // packed 1536x768 (end 6389760)

// ---------------------------------------------------------------------------
// Conversion dispatch: 2784 blocks (weights -> packed frags; inp/mixed -> bf16)
// ---------------------------------------------------------------------------
__global__ __launch_bounds__(256) void k_conv(const float* __restrict__ inp,
                                              const float* __restrict__ is_first,
                                              const float* __restrict__ init_inp,
                                              const float* __restrict__ mu,
                                              const float* __restrict__ mixW,
                                              const float* __restrict__ layerW,
                                              const float* __restrict__ projW,
                                              const float* __restrict__ W1,
                                              const float* __restrict__ W2,
                                              const float* __restrict__ W3,
                                              short* __restrict__ wsb) {
  const int blk = blockIdx.x;
  const int tid = threadIdx.x;
  if (blk >= 2592) {
    if (blk < 2688) {      // inp -> bf16
      const int idx = (blk - 2592) * 2048 + tid * 8;
      float4 a = *(const float4*)&inp[idx], b = *(const float4*)&inp[idx + 4];
      *(bf16x8*)&wsb[PB_INP + idx] = cvt8(a, b);
    } else {               // mixed -> bf16
      const int idx = (blk - 2688) * 2048 + tid * 8;
      const int c = idx % INP_D, tok = idx / INP_D;
      const int t = tok >> 2, b = tok & 3;
      const float fr = (t == 0) ? 1.0f : is_first[tok];
      const float* lastp = (fr > 0.5f) ? &init_inp[b * INP_D + c] : &inp[idx - 4 * INP_D];
      float4 x0 = *(const float4*)&inp[idx], x1 = *(const float4*)&inp[idx + 4];
      float4 l0 = *(const float4*)&lastp[0], l1 = *(const float4*)&lastp[4];
      float4 m0 = *(const float4*)&mu[c],    m1 = *(const float4*)&mu[c + 4];
      float4 r0, r1;
      r0.x = m0.x * x0.x + (1.0f - m0.x) * l0.x;
      r0.y = m0.y * x0.y + (1.0f - m0.y) * l0.y;
      r0.z = m0.z * x0.z + (1.0f - m0.z) * l0.z;
      r0.w = m0.w * x0.w + (1.0f - m0.w) * l0.w;
      r1.x = m1.x * x1.x + (1.0f - m1.x) * l1.x;
      r1.y = m1.y * x1.y + (1.0f - m1.y) * l1.y;
      r1.z = m1.z * x1.z + (1.0f - m1.z) * l1.z;
      r1.w = m1.w * x1.w + (1.0f - m1.w) * l1.w;
      *(bf16x8*)&wsb[PB_MIXED + idx] = cvt8(r0, r1);
    }
    return;
  }
  const float* src; short* dst; int N, kb, nb64;
  if (blk < 144)        { src = mixW;   dst = wsb + PK_MIX;   N = 384;  int r = blk;        kb = r / 6;  nb64 = r % 6; }
  else if (blk < 720)   { src = layerW; dst = wsb + PK_LAYER; N = 1536; int r = blk - 144;  kb = r / 24; nb64 = r % 24; }
  else if (blk < 864)   { src = projW;  dst = wsb + PK_PROJ;  N = 768;  int r = blk - 720;  kb = r / 12; nb64 = r % 12; }
  else if (blk < 1440)  { src = W1;     dst = wsb + PK_W1;    N = 1536; int r = blk - 864;  kb = r / 24; nb64 = r % 24; }
  else if (blk < 2016)  { src = W2;     dst = wsb + PK_W2;    N = 1536; int r = blk - 1440; kb = r / 24; nb64 = r % 24; }
  else                  { src = W3;     dst = wsb + PK_W3;    N = 768;  int r = blk - 2016; kb = r / 12; nb64 = r % 12; }

  __shared__ float lds[32][68];
  {
    const int r = tid >> 3, c8 = (tid & 7) * 8;
    const float* p = &src[(size_t)(kb * 32 + r) * N + nb64 * 64 + c8];
    *(float4*)&lds[r][c8]     = *(const float4*)p;
    *(float4*)&lds[r][c8 + 4] = *(const float4*)(p + 4);
  }
  __syncthreads();
  {
    const int nb = tid >> 6, lane = tid & 63, g = lane >> 4, c = lane & 15;
    unsigned int w[4];
#pragma unroll
    for (int jj = 0; jj < 4; ++jj) {
      unsigned short lo = (unsigned short)f2b(lds[g * 8 + jj * 2][nb * 16 + c]);
      unsigned short hi = (unsigned short)f2b(lds[g * 8 + jj * 2 + 1][nb * 16 + c]);
      w[jj] = (unsigned int)lo | ((unsigned int)hi << 16);
    }
    const int N16 = N >> 4;
    size_t o = ((size_t)kb * N16 + (nb64 * 4 + nb)) * 512 + lane * 8;
    uint4 pk; pk.x = w[0]; pk.y = w[1]; pk.z = w[2]; pk.w = w[3];
    *(uint4*)&dst[o] = pk;
  }
}

// ---------------------------------------------------------------------------
// MFMA core (SUBT 16-col subtiles). A loads are direct bf16 dwordx4.
// ---------------------------------------------------------------------------
template<int KSTEPS, int SUBT, bool DUAL, int ASTRIDE>
__device__ __forceinline__ void mm_core(const short* __restrict__ Arow, int kg,
                                        const short* __restrict__ B1, int bn1, int N16a,
                                        const short* __restrict__ B2, int bn2, int N16b,
                                        int lane, f32x4* acc1, f32x4* acc2) {
  bf16x8 a_c = *(const bf16x8*)&Arow[kg];
  bf16x8 b1c[SUBT], b2c[SUBT];
#pragma unroll
  for (int s = 0; s < SUBT; ++s)
    b1c[s] = *(const bf16x8*)&B1[((size_t)(bn1 + s)) * 512 + lane * 8];
  if constexpr (DUAL) {
#pragma unroll
    for (int s = 0; s < SUBT; ++s)
      b2c[s] = *(const bf16x8*)&B2[((size_t)(bn2 + s)) * 512 + lane * 8];
  }
#pragma unroll 2
  for (int kb = 0; kb < KSTEPS; ++kb) {
    bf16x8 a_n = a_c;
    bf16x8 b1n[SUBT], b2n[SUBT];
    if (kb + 1 < KSTEPS) {
      a_n = *(const bf16x8*)&Arow[(kb + 1) * 32 + kg];
#pragma unroll
      for (int s = 0; s < SUBT; ++s)
        b1n[s] = *(const bf16x8*)&B1[((size_t)(kb + 1) * N16a + bn1 + s) * 512 + lane * 8];
      if constexpr (DUAL) {
#pragma unroll
        for (int s = 0; s < SUBT; ++s)
          b2n[s] = *(const bf16x8*)&B2[((size_t)(kb + 1) * N16b + bn2 + s) * 512 + lane * 8];
      }
    }
#pragma unroll
    for (int s = 0; s < SUBT; ++s)
      acc1[s] = __builtin_amdgcn_mfma_f32_16x16x32_bf16(a_c, b1c[s], acc1[s], 0, 0, 0);
    if constexpr (DUAL) {
#pragma unroll
      for (int s = 0; s < SUBT; ++s)
        acc2[s] = __builtin_amdgcn_mfma_f32_16x16x32_bf16(a_c, b2c[s], acc2[s], 0, 0, 0);
    }
    a_c = a_n;
#pragma unroll
    for (int s = 0; s < SUBT; ++s) b1c[s] = b1n[s];
    if constexpr (DUAL) {
#pragma unroll
      for (int s = 0; s < SUBT; ++s) b2c[s] = b2n[s];
    }
  }
}

#define WAVE_SETUP  const int tid = threadIdx.x, w = tid >> 6, l = tid & 63; \
                    const int m0 = blockIdx.x * 64; \
                    const int rowA = m0 + w * 16 + (l & 15); \
                    const int kg = (l >> 4) * 8; (void)kg;

// ---------------------------------------------------------------------------
// Merged fg + parts. Grid (4, 48), 32-col wave tiles. A = mixed_bf / inp_bf.
// ---------------------------------------------------------------------------
__global__ __launch_bounds__(256) void k_qkvfg(const short* __restrict__ inp_bf,
                                               const short* __restrict__ mixed_bf,
                                               const short* __restrict__ Mixp,
                                               const short* __restrict__ Lp,
                                               const float* __restrict__ drops,
                                               float* __restrict__ forget,
                                               float* __restrict__ query,
                                               float* __restrict__ keyv,
                                               float* __restrict__ value) {
  WAVE_SETUP
  const int y = blockIdx.y;
  if (y < 12) {
    const int n0 = y * 32, bn = y * 2;
    const short* Arow = &mixed_bf[(size_t)rowA * INP_D];
    f32x4 acc[2] = {(f32x4){0.f,0.f,0.f,0.f}, (f32x4){0.f,0.f,0.f,0.f}};
    mm_core<24, 2, false, INP_D>(Arow, kg, Mixp, bn, 24, nullptr, 0, 0, l, acc, nullptr);
#pragma unroll
    for (int i = 0; i < 4; ++i) {
      const int row = m0 + w * 16 + ((l >> 4) << 2) + i;
      const float d = drops[row];
#pragma unroll
      for (int s = 0; s < 2; ++s) {
        const int col = n0 + s * 16 + (l & 15);
        forget[(size_t)row * Q_D + col] = (sigf(acc[s][i]) - 1.0f) * d + 1.0f;
      }
    }
    return;
  }
  const short* Arow = &inp_bf[(size_t)rowA * INP_D];
  if (y < 36) {
    const bool isq = (y < 24);
    const int yy = isq ? y - 12 : y - 24;
    float* dst = isq ? query : keyv;
    const int bn = (isq ? 0 : 24) + yy * 2;
    f32x4 acc[2] = {(f32x4){0.f,0.f,0.f,0.f}, (f32x4){0.f,0.f,0.f,0.f}};
    mm_core<24, 2, false, INP_D>(Arow, kg, Lp, bn, 96, nullptr, 0, 0, l, acc, nullptr);
#pragma unroll
    for (int i = 0; i < 4; ++i) {
      const int row = m0 + w * 16 + ((l >> 4) << 2) + i;
      const float d = drops[row];
#pragma unroll
      for (int s = 0; s < 2; ++s) {
        const int col = yy * 32 + s * 16 + (l & 15);
        dst[(size_t)row * Q_D + col] = elu1f(acc[s][i] * d);
      }
    }
  } else {
    const int q = y - 36;
    const int bn_r = 48 + q * 2, bn_v = 72 + q * 2;
    f32x4 a1[2] = {(f32x4){0.f,0.f,0.f,0.f}, (f32x4){0.f,0.f,0.f,0.f}};
    f32x4 a2[2] = {(f32x4){0.f,0.f,0.f,0.f}, (f32x4){0.f,0.f,0.f,0.f}};
    mm_core<24, 2, true, INP_D>(Arow, kg, Lp, bn_r, 96, Lp, bn_v, 96, l, a1, a2);
#pragma unroll
    for (int i = 0; i < 4; ++i) {
      const int row = m0 + w * 16 + ((l >> 4) << 2) + i;
      const float d = drops[row];
#pragma unroll
      for (int s = 0; s < 2; ++s) {
        const int col = q * 32 + s * 16 + (l & 15);
        value[(size_t)row * E_D + col] = sigf(a1[s][i] * d) * (a2[s][i] * d);
      }
    }
  }
}

// ---------------------------------------------------------------------------
// proj: hpre = attn_bf @ proj_W + inp. Grid (4, 24).
// ---------------------------------------------------------------------------
__global__ __launch_bounds__(256) void k_proj(const short* __restrict__ attn_bf,
                                              const short* __restrict__ Bp,
                                              const float* __restrict__ inp,
                                              float* __restrict__ hpre) {
  WAVE_SETUP
  const int n0 = blockIdx.y * 32, bn = blockIdx.y * 2;
  const short* Arow = &attn_bf[(size_t)rowA * E_D];
  f32x4 acc[2] = {(f32x4){0.f,0.f,0.f,0.f}, (f32x4){0.f,0.f,0.f,0.f}};
  mm_core<12, 2, false, E_D>(Arow, kg, Bp, bn, 48, nullptr, 0, 0, l, acc, nullptr);
#pragma unroll
  for (int i = 0; i < 4; ++i) {
    const int row = m0 + w * 16 + ((l >> 4) << 2) + i;
#pragma unroll
    for (int s = 0; s < 2; ++s) {
      const int col = n0 + s * 16 + (l & 15);
      hpre[(size_t)row * INP_D + col] = acc[s][i] + inp[(size_t)row * INP_D + col];
    }
  }
}

// ---------------------------------------------------------------------------
// FFN dual: g_bf = bf16(silu(h@W1) * (h@W2)). Grid (4, 48).
// ---------------------------------------------------------------------------
__global__ __launch_bounds__(256) void k_ffn(const short* __restrict__ h_bf,
                                             const short* __restrict__ W1p,
                                             const short* __restrict__ W2p,
                                             short* __restrict__ g_bf) {
  WAVE_SETUP
  const int n0 = blockIdx.y * 32, bn = blockIdx.y * 2;
  const short* Arow = &h_bf[(size_t)rowA * INP_D];
  f32x4 a1[2] = {(f32x4){0.f,0.f,0.f,0.f}, (f32x4){0.f,0.f,0.f,0.f}};
  f32x4 a2[2] = {(f32x4){0.f,0.f,0.f,0.f}, (f32x4){0.f,0.f,0.f,0.f}};
  mm_core<24, 2, true, INP_D>(Arow, kg, W1p, bn, 96, W2p, bn, 96, l, a1, a2);
#pragma unroll
  for (int i = 0; i < 4; ++i) {
    const int row = m0 + w * 16 + ((l >> 4) << 2) + i;
#pragma unroll
    for (int s = 0; s < 2; ++s) {
      const int col = n0 + s * 16 + (l & 15);
      const float v1 = a1[s][i], v2 = a2[s][i];
      g_bf[(size_t)row * DFF_D + col] = f2b(v1 * sigf(v1) * v2);
    }
  }
}

// ---------------------------------------------------------------------------
// out = g_bf @ W3. Grid (4, 24).
// ---------------------------------------------------------------------------
__global__ __launch_bounds__(256) void k_out(const short* __restrict__ g_bf,
                                             const short* __restrict__ Bp,
                                             float* __restrict__ out) {
  WAVE_SETUP
  const int n0 = blockIdx.y * 32, bn = blockIdx.y * 2;
  const short* Arow = &g_bf[(size_t)rowA * DFF_D];
  f32x4 acc[2] = {(f32x4){0.f,0.f,0.f,0.f}, (f32x4){0.f,0.f,0.f,0.f}};
  mm_core<48, 2, false, DFF_D>(Arow, kg, Bp, bn, 48, nullptr, 0, 0, l, acc, nullptr);
#pragma unroll
  for (int i = 0; i < 4; ++i) {
    const int row = m0 + w * 16 + ((l >> 4) << 2) + i;
#pragma unroll
    for (int s = 0; s < 2; ++s) {
      const int col = n0 + s * 16 + (l & 15);
      out[(size_t)row * INP_D + col] = acc[s][i];
    }
  }
}

// ---------------------------------------------------------------------------
// Segmented scan — EXACT R8/R9 proven two-sync structure (reverted from R10's
// double-buffer, which exposed load latency and ran 69.8 vs <=42 us).
// Grid (6, 8, 4), 256 threads, 12 states/thread.
// ---------------------------------------------------------------------------
__global__ __launch_bounds__(256) void k_scan(const float* __restrict__ forget,
                                              const float* __restrict__ query,
                                              const float* __restrict__ keyv,
                                              const float* __restrict__ value,
                                              const float* __restrict__ is_first,
                                              const float* __restrict__ init_state,
                                              float* __restrict__ patt) {
  __shared__ float stg[144];
  __shared__ float pacc[256];
  const int tid = threadIdx.x;
  const int e  = blockIdx.x * 64 + (tid & 63);
  const int qg = tid >> 6;
  const int qc = blockIdx.y;
  const int b  = blockIdx.z;
  const int q0 = qc * 48 + qg * 12;

  float s[12], ini[12];
#pragma unroll
  for (int j = 0; j < 12; ++j) {
    ini[j] = init_state[((size_t)b * Q_D + q0 + j) * E_D + e];
    s[j]   = ini[j];
  }

  float stage_r = 0.0f, v_r, if_r;
  {
    const int tok = b;
    if (tid < 144) {
      const int which = tid / 48, o = tid % 48;
      const float* src = which == 0 ? forget : (which == 1 ? keyv : query);
      stage_r = src[(size_t)tok * Q_D + qc * 48 + o];
    }
    v_r  = value[(size_t)tok * E_D + e];
    if_r = 0.0f;
  }

  for (int t = 0; t < T_DIM; ++t) {
    const int tok = t * B_DIM + b;
    if (tid < 144) stg[tid] = stage_r;
    const float v  = v_r;
    const float ff = if_r;
    __syncthreads();
    if (t + 1 < T_DIM) {
      const int tok1 = tok + B_DIM;
      if (tid < 144) {
        const int which = tid / 48, o = tid % 48;
        const float* src = which == 0 ? forget : (which == 1 ? keyv : query);
        stage_r = src[(size_t)tok1 * Q_D + qc * 48 + o];
      }
      v_r  = value[(size_t)tok1 * E_D + e];
      if_r = is_first[tok1];
    }
    if (ff > 0.5f) {
#pragma unroll
      for (int j = 0; j < 12; ++j) s[j] = ini[j];
    }
    const float4* f4 = (const float4*)&stg[qg * 12];
    const float4* k4 = (const float4*)&stg[48 + qg * 12];
    const float4* q4 = (const float4*)&stg[96 + qg * 12];
    float p = 0.0f;
#pragma unroll
    for (int jj = 0; jj < 3; ++jj) {
      const float4 fv = f4[jj], kv = k4[jj], qv = q4[jj];
#pragma unroll
      for (int j2 = 0; j2 < 4; ++j2) {
        const int sj = jj * 4 + j2;
        s[sj] = fmaf((&fv.x)[j2], s[sj], (&kv.x)[j2] * v);
        p     = fmaf((&qv.x)[j2], s[sj], p);
      }
    }
    pacc[tid] = p;
    __syncthreads();
    if (tid < 64) {
      float r = pacc[tid] + pacc[tid + 64] + pacc[tid + 128] + pacc[tid + 192];
      patt[((size_t)qc * NTOK + tok) * E_D + blockIdx.x * 64 + tid] = r;
    }
    __syncthreads();
  }
}

// sum 8 scan slabs + RMS norm -> attn_bf (bf16)
__global__ __launch_bounds__(128) void ep_rms(const float* __restrict__ patt,
                                              const float* __restrict__ rms_w,
                                              short* __restrict__ attn_bf) {
  const int tok = blockIdx.x, tid = threadIdx.x;
  float x[3], ss = 0.0f;
#pragma unroll
  for (int i = 0; i < 3; ++i) {
    const int e = i * 128 + tid;
    float a = 0.0f;
#pragma unroll
    for (int qc = 0; qc < 8; ++qc) a += patt[((size_t)qc * NTOK + tok) * E_D + e];
    x[i] = a;
    ss = fmaf(a, a, ss);
  }
#pragma unroll
  for (int off = 32; off; off >>= 1) ss += __shfl_down(ss, off, 64);
  __shared__ float r[2];
  const int wid = tid >> 6, lane = tid & 63;
  if (lane == 0) r[wid] = ss;
  __syncthreads();
  ss = r[0] + r[1];
  const float sc = rsqrtf(ss * (1.0f / E_D) + 1e-6f);
#pragma unroll
  for (int i = 0; i < 3; ++i) {
    const int e = i * 128 + tid;
    attn_bf[(size_t)tok * E_D + e] = f2b(x[i] * sc * rms_w[e]);
  }
}

// LayerNorm over hpre -> h_bf (bf16)
__global__ __launch_bounds__(256) void ep_ln(const float* __restrict__ hpre,
                                             const float* __restrict__ ln_w,
                                             const float* __restrict__ ln_b,
                                             short* __restrict__ h_bf) {
  const int tok = blockIdx.x, tid = threadIdx.x;
  float x[3], s1 = 0.0f, s2 = 0.0f;
#pragma unroll
  for (int i = 0; i < 3; ++i) {
    x[i] = hpre[(size_t)tok * INP_D + i * 256 + tid];
    s1 += x[i];
    s2 = fmaf(x[i], x[i], s2);
  }
#pragma unroll
  for (int off = 32; off; off >>= 1) {
    s1 += __shfl_down(s1, off, 64);
    s2 += __shfl_down(s2, off, 64);
  }
  __shared__ float r1[4], r2[4];
  const int wid = tid >> 6, lane = tid & 63;
  if (lane == 0) { r1[wid] = s1; r2[wid] = s2; }
  __syncthreads();
  s1 = r1[0] + r1[1] + r1[2] + r1[3];
  s2 = r2[0] + r2[1] + r2[2] + r2[3];
  const float mean = s1 * (1.0f / INP_D);
  const float var  = s2 * (1.0f / INP_D) - mean * mean;
  const float sc   = rsqrtf(var + 1e-5f);
#pragma unroll
  for (int i = 0; i < 3; ++i) {
    const int c = i * 256 + tid;
    h_bf[(size_t)tok * INP_D + c] = f2b((x[i] - mean) * sc * ln_w[c] + ln_b[c]);
  }
}

extern "C" void kernel_launch(void* const* d_in, const int* in_sizes, int n_in,
                              void* d_out, int out_size, void* d_ws, size_t ws_size,
                              hipStream_t stream) {
  (void)in_sizes; (void)n_in; (void)out_size; (void)ws_size;
  const float* inp        = (const float*)d_in[0];
  const float* is_first   = (const float*)d_in[1];
  const float* drops      = (const float*)d_in[2];
  const float* init_inp   = (const float*)d_in[3];
  const float* init_state = (const float*)d_in[4];
  const float* mix_mu     = (const float*)d_in[5];
  const float* mix_W      = (const float*)d_in[6];
  const float* layer_W    = (const float*)d_in[7];
  const float* proj_W     = (const float*)d_in[8];
  const float* rms_w      = (const float*)d_in[9];
  const float* ln_w       = (const float*)d_in[10];
  const float* ln_b       = (const float*)d_in[11];
  const float* W1         = (const float*)d_in[12];
  const float* W2         = (const float*)d_in[13];
  const float* W3         = (const float*)d_in[14];
  float* out = (float*)d_out;
  float* ws  = (float*)d_ws;
  short* wsb = (short*)(ws + WS_BF);

  float* forget = ws + WS_FORGET;
  float* query  = ws + WS_QUERY;
  float* keyv   = ws + WS_KEYV;
  float* value  = ws + WS_VALUE;
  float* patt   = ws + WS_PATT;
  float* hpre   = ws + WS_HPRE;

  k_conv<<<2784, 256, 0, stream>>>(inp, is_first, init_inp, mix_mu,
                                   mix_W, layer_W, proj_W, W1, W2, W3, wsb);
  k_qkvfg<<<dim3(4, 48), 256, 0, stream>>>(wsb + PB_INP, wsb + PB_MIXED,
                                           wsb + PK_MIX, wsb + PK_LAYER, drops,
                                           forget, query, keyv, value);
  k_scan<<<dim3(6, 8, 4), 256, 0, stream>>>(forget, query, keyv, value,
                                            is_first, init_state, patt);
  ep_rms<<<NTOK, 128, 0, stream>>>(patt, rms_w, wsb + PB_ATTN);
  k_proj<<<dim3(4, 24), 256, 0, stream>>>(wsb + PB_ATTN, wsb + PK_PROJ, inp, hpre);
  ep_ln<<<NTOK, 256, 0, stream>>>(hpre, ln_w, ln_b, wsb + PB_H);
  k_ffn<<<dim3(4, 48), 256, 0, stream>>>(wsb + PB_H, wsb + PK_W1, wsb + PK_W2, wsb + PB_G);
  k_out<<<dim3(4, 24), 256, 0, stream>>>(wsb + PB_G, wsb + PK_W3, out);
}

// Round 12
// 169.524 us; speedup vs baseline: 1.1720x; 1.0057x over previous
//
#include <hip/hip_runtime.h>
#include <hip/hip_bf16.h>

#define T_DIM 64
#define B_DIM 4
#define INP_D 768
#define Q_D   384
#define E_D   384
#define DFF_D 1536
#define NTOK  256

typedef short bf16x8 __attribute__((ext_vector_type(8)));
typedef float f32x4  __attribute__((ext_vector_type(4)));

__device__ __forceinline__ float sigf(float x)  { return 1.0f / (1.0f + __expf(-x)); }
__device__ __forceinline__ float elu1f(float x) { return x > 0.0f ? x + 1.0f : __expf(x); }

__device__ __forceinline__ short f2b(float x) {
  union { __hip_bfloat16 b; short s; } u;
  u.b = __float2bfloat16(x);
  return u.s;
}
__device__ __forceinline__ bf16x8 cvt8(float4 a, float4 b) {
  bf16x8 r;
  r[0] = f2b(a.x); r[1] = f2b(a.y); r[2] = f2b(a.z); r[3] = f2b(a.w);
  r[4] = f2b(b.x); r[5] = f2b(b.y); r[6] = f2b(b.z); r[7] = f2b(b.w);
  return r;
}

// ---------------------------------------------------------------------------
// Workspace: f32 region [0,1376256) then bf16 region (short offsets below).
// ---------------------------------------------------------------------------
#define WS_FORGET 0
#define WS_QUERY  98304
#define WS_KEYV   196608
#define WS_VALUE  294912
#define WS_PATT   393216      // [8][256][384] f32
#define WS_HPRE   1179648     // [256][768] f32
#define WS_BF     1376256     // bf16 region start (f32 offset)
// bf16-element offsets:
#define PB_INP   0            // [256][768]
#define PB_MIXED 196608       // [256][768]
#define PB_ATTN  393216       // [256][384]
#define PB_H     491520       // [256][768]
#define PB_G     688128       // [256][1536]
#define PK_MIX   1081344      // packed 768x384
#define PK_LAYER 1376256      // packed 768x1536
#define PK_PROJ  2555904      // packed 384x768
#define PK_W1    2850816      // packed 768x1536
#define PK_W2    4030464      // packed 768x1536
#define PK_W3    5210112      // packed 1536x768 (end 6389760)

// ---------------------------------------------------------------------------
// Conversion dispatch: 2784 blocks (weights -> packed frags; inp/mixed -> bf16)
// ---------------------------------------------------------------------------
__global__ __launch_bounds__(256) void k_conv(const float* __restrict__ inp,
                                              const float* __restrict__ is_first,
                                              const float* __restrict__ init_inp,
                                              const float* __restrict__ mu,
                                              const float* __restrict__ mixW,
                                              const float* __restrict__ layerW,
                                              const float* __restrict__ projW,
                                              const float* __restrict__ W1,
                                              const float* __restrict__ W2,
                                              const float* __restrict__ W3,
                                              short* __restrict__ wsb) {
  const int blk = blockIdx.x;
  const int tid = threadIdx.x;
  if (blk >= 2592) {
    if (blk < 2688) {      // inp -> bf16
      const int idx = (blk - 2592) * 2048 + tid * 8;
      float4 a = *(const float4*)&inp[idx], b = *(const float4*)&inp[idx + 4];
      *(bf16x8*)&wsb[PB_INP + idx] = cvt8(a, b);
    } else {               // mixed -> bf16
      const int idx = (blk - 2688) * 2048 + tid * 8;
      const int c = idx % INP_D, tok = idx / INP_D;
      const int t = tok >> 2, b = tok & 3;
      const float fr = (t == 0) ? 1.0f : is_first[tok];
      const float* lastp = (fr > 0.5f) ? &init_inp[b * INP_D + c] : &inp[idx - 4 * INP_D];
      float4 x0 = *(const float4*)&inp[idx], x1 = *(const float4*)&inp[idx + 4];
      float4 l0 = *(const float4*)&lastp[0], l1 = *(const float4*)&lastp[4];
      float4 m0 = *(const float4*)&mu[c],    m1 = *(const float4*)&mu[c + 4];
      float4 r0, r1;
      r0.x = m0.x * x0.x + (1.0f - m0.x) * l0.x;
      r0.y = m0.y * x0.y + (1.0f - m0.y) * l0.y;
      r0.z = m0.z * x0.z + (1.0f - m0.z) * l0.z;
      r0.w = m0.w * x0.w + (1.0f - m0.w) * l0.w;
      r1.x = m1.x * x1.x + (1.0f - m1.x) * l1.x;
      r1.y = m1.y * x1.y + (1.0f - m1.y) * l1.y;
      r1.z = m1.z * x1.z + (1.0f - m1.z) * l1.z;
      r1.w = m1.w * x1.w + (1.0f - m1.w) * l1.w;
      *(bf16x8*)&wsb[PB_MIXED + idx] = cvt8(r0, r1);
    }
    return;
  }
  const float* src; short* dst; int N, kb, nb64;
  if (blk < 144)        { src = mixW;   dst = wsb + PK_MIX;   N = 384;  int r = blk;        kb = r / 6;  nb64 = r % 6; }
  else if (blk < 720)   { src = layerW; dst = wsb + PK_LAYER; N = 1536; int r = blk - 144;  kb = r / 24; nb64 = r % 24; }
  else if (blk < 864)   { src = projW;  dst = wsb + PK_PROJ;  N = 768;  int r = blk - 720;  kb = r / 12; nb64 = r % 12; }
  else if (blk < 1440)  { src = W1;     dst = wsb + PK_W1;    N = 1536; int r = blk - 864;  kb = r / 24; nb64 = r % 24; }
  else if (blk < 2016)  { src = W2;     dst = wsb + PK_W2;    N = 1536; int r = blk - 1440; kb = r / 24; nb64 = r % 24; }
  else                  { src = W3;     dst = wsb + PK_W3;    N = 768;  int r = blk - 2016; kb = r / 12; nb64 = r % 12; }

  __shared__ float lds[32][68];
  {
    const int r = tid >> 3, c8 = (tid & 7) * 8;
    const float* p = &src[(size_t)(kb * 32 + r) * N + nb64 * 64 + c8];
    *(float4*)&lds[r][c8]     = *(const float4*)p;
    *(float4*)&lds[r][c8 + 4] = *(const float4*)(p + 4);
  }
  __syncthreads();
  {
    const int nb = tid >> 6, lane = tid & 63, g = lane >> 4, c = lane & 15;
    unsigned int w[4];
#pragma unroll
    for (int jj = 0; jj < 4; ++jj) {
      unsigned short lo = (unsigned short)f2b(lds[g * 8 + jj * 2][nb * 16 + c]);
      unsigned short hi = (unsigned short)f2b(lds[g * 8 + jj * 2 + 1][nb * 16 + c]);
      w[jj] = (unsigned int)lo | ((unsigned int)hi << 16);
    }
    const int N16 = N >> 4;
    size_t o = ((size_t)kb * N16 + (nb64 * 4 + nb)) * 512 + lane * 8;
    uint4 pk; pk.x = w[0]; pk.y = w[1]; pk.z = w[2]; pk.w = w[3];
    *(uint4*)&dst[o] = pk;
  }
}

// ---------------------------------------------------------------------------
// MFMA core (SUBT 16-col subtiles). A loads are direct bf16 dwordx4.
// ---------------------------------------------------------------------------
template<int KSTEPS, int SUBT, bool DUAL, int ASTRIDE>
__device__ __forceinline__ void mm_core(const short* __restrict__ Arow, int kg,
                                        const short* __restrict__ B1, int bn1, int N16a,
                                        const short* __restrict__ B2, int bn2, int N16b,
                                        int lane, f32x4* acc1, f32x4* acc2) {
  bf16x8 a_c = *(const bf16x8*)&Arow[kg];
  bf16x8 b1c[SUBT], b2c[SUBT];
#pragma unroll
  for (int s = 0; s < SUBT; ++s)
    b1c[s] = *(const bf16x8*)&B1[((size_t)(bn1 + s)) * 512 + lane * 8];
  if constexpr (DUAL) {
#pragma unroll
    for (int s = 0; s < SUBT; ++s)
      b2c[s] = *(const bf16x8*)&B2[((size_t)(bn2 + s)) * 512 + lane * 8];
  }
#pragma unroll 2
  for (int kb = 0; kb < KSTEPS; ++kb) {
    bf16x8 a_n = a_c;
    bf16x8 b1n[SUBT], b2n[SUBT];
    if (kb + 1 < KSTEPS) {
      a_n = *(const bf16x8*)&Arow[(kb + 1) * 32 + kg];
#pragma unroll
      for (int s = 0; s < SUBT; ++s)
        b1n[s] = *(const bf16x8*)&B1[((size_t)(kb + 1) * N16a + bn1 + s) * 512 + lane * 8];
      if constexpr (DUAL) {
#pragma unroll
        for (int s = 0; s < SUBT; ++s)
          b2n[s] = *(const bf16x8*)&B2[((size_t)(kb + 1) * N16b + bn2 + s) * 512 + lane * 8];
      }
    }
#pragma unroll
    for (int s = 0; s < SUBT; ++s)
      acc1[s] = __builtin_amdgcn_mfma_f32_16x16x32_bf16(a_c, b1c[s], acc1[s], 0, 0, 0);
    if constexpr (DUAL) {
#pragma unroll
      for (int s = 0; s < SUBT; ++s)
        acc2[s] = __builtin_amdgcn_mfma_f32_16x16x32_bf16(a_c, b2c[s], acc2[s], 0, 0, 0);
    }
    a_c = a_n;
#pragma unroll
    for (int s = 0; s < SUBT; ++s) b1c[s] = b1n[s];
    if constexpr (DUAL) {
#pragma unroll
      for (int s = 0; s < SUBT; ++s) b2c[s] = b2n[s];
    }
  }
}

#define WAVE_SETUP  const int tid = threadIdx.x, w = tid >> 6, l = tid & 63; \
                    const int m0 = blockIdx.x * 64; \
                    const int rowA = m0 + w * 16 + (l & 15); \
                    const int kg = (l >> 4) * 8; (void)kg;

// ---------------------------------------------------------------------------
// Merged fg + parts. Grid (4, 48), 32-col wave tiles. A = mixed_bf / inp_bf.
// ---------------------------------------------------------------------------
__global__ __launch_bounds__(256) void k_qkvfg(const short* __restrict__ inp_bf,
                                               const short* __restrict__ mixed_bf,
                                               const short* __restrict__ Mixp,
                                               const short* __restrict__ Lp,
                                               const float* __restrict__ drops,
                                               float* __restrict__ forget,
                                               float* __restrict__ query,
                                               float* __restrict__ keyv,
                                               float* __restrict__ value) {
  WAVE_SETUP
  const int y = blockIdx.y;
  if (y < 12) {
    const int n0 = y * 32, bn = y * 2;
    const short* Arow = &mixed_bf[(size_t)rowA * INP_D];
    f32x4 acc[2] = {(f32x4){0.f,0.f,0.f,0.f}, (f32x4){0.f,0.f,0.f,0.f}};
    mm_core<24, 2, false, INP_D>(Arow, kg, Mixp, bn, 24, nullptr, 0, 0, l, acc, nullptr);
#pragma unroll
    for (int i = 0; i < 4; ++i) {
      const int row = m0 + w * 16 + ((l >> 4) << 2) + i;
      const float d = drops[row];
#pragma unroll
      for (int s = 0; s < 2; ++s) {
        const int col = n0 + s * 16 + (l & 15);
        forget[(size_t)row * Q_D + col] = (sigf(acc[s][i]) - 1.0f) * d + 1.0f;
      }
    }
    return;
  }
  const short* Arow = &inp_bf[(size_t)rowA * INP_D];
  if (y < 36) {
    const bool isq = (y < 24);
    const int yy = isq ? y - 12 : y - 24;
    float* dst = isq ? query : keyv;
    const int bn = (isq ? 0 : 24) + yy * 2;
    f32x4 acc[2] = {(f32x4){0.f,0.f,0.f,0.f}, (f32x4){0.f,0.f,0.f,0.f}};
    mm_core<24, 2, false, INP_D>(Arow, kg, Lp, bn, 96, nullptr, 0, 0, l, acc, nullptr);
#pragma unroll
    for (int i = 0; i < 4; ++i) {
      const int row = m0 + w * 16 + ((l >> 4) << 2) + i;
      const float d = drops[row];
#pragma unroll
      for (int s = 0; s < 2; ++s) {
        const int col = yy * 32 + s * 16 + (l & 15);
        dst[(size_t)row * Q_D + col] = elu1f(acc[s][i] * d);
      }
    }
  } else {
    const int q = y - 36;
    const int bn_r = 48 + q * 2, bn_v = 72 + q * 2;
    f32x4 a1[2] = {(f32x4){0.f,0.f,0.f,0.f}, (f32x4){0.f,0.f,0.f,0.f}};
    f32x4 a2[2] = {(f32x4){0.f,0.f,0.f,0.f}, (f32x4){0.f,0.f,0.f,0.f}};
    mm_core<24, 2, true, INP_D>(Arow, kg, Lp, bn_r, 96, Lp, bn_v, 96, l, a1, a2);
#pragma unroll
    for (int i = 0; i < 4; ++i) {
      const int row = m0 + w * 16 + ((l >> 4) << 2) + i;
      const float d = drops[row];
#pragma unroll
      for (int s = 0; s < 2; ++s) {
        const int col = q * 32 + s * 16 + (l & 15);
        value[(size_t)row * E_D + col] = sigf(a1[s][i] * d) * (a2[s][i] * d);
      }
    }
  }
}

// ---------------------------------------------------------------------------
// proj: hpre = attn_bf @ proj_W + inp. Grid (4, 24).
// ---------------------------------------------------------------------------
__global__ __launch_bounds__(256) void k_proj(const short* __restrict__ attn_bf,
                                              const short* __restrict__ Bp,
                                              const float* __restrict__ inp,
                                              float* __restrict__ hpre) {
  WAVE_SETUP
  const int n0 = blockIdx.y * 32, bn = blockIdx.y * 2;
  const short* Arow = &attn_bf[(size_t)rowA * E_D];
  f32x4 acc[2] = {(f32x4){0.f,0.f,0.f,0.f}, (f32x4){0.f,0.f,0.f,0.f}};
  mm_core<12, 2, false, E_D>(Arow, kg, Bp, bn, 48, nullptr, 0, 0, l, acc, nullptr);
#pragma unroll
  for (int i = 0; i < 4; ++i) {
    const int row = m0 + w * 16 + ((l >> 4) << 2) + i;
#pragma unroll
    for (int s = 0; s < 2; ++s) {
      const int col = n0 + s * 16 + (l & 15);
      hpre[(size_t)row * INP_D + col] = acc[s][i] + inp[(size_t)row * INP_D + col];
    }
  }
}

// ---------------------------------------------------------------------------
// FFN dual: g_bf = bf16(silu(h@W1) * (h@W2)). Grid (4, 48).
// ---------------------------------------------------------------------------
__global__ __launch_bounds__(256) void k_ffn(const short* __restrict__ h_bf,
                                             const short* __restrict__ W1p,
                                             const short* __restrict__ W2p,
                                             short* __restrict__ g_bf) {
  WAVE_SETUP
  const int n0 = blockIdx.y * 32, bn = blockIdx.y * 2;
  const short* Arow = &h_bf[(size_t)rowA * INP_D];
  f32x4 a1[2] = {(f32x4){0.f,0.f,0.f,0.f}, (f32x4){0.f,0.f,0.f,0.f}};
  f32x4 a2[2] = {(f32x4){0.f,0.f,0.f,0.f}, (f32x4){0.f,0.f,0.f,0.f}};
  mm_core<24, 2, true, INP_D>(Arow, kg, W1p, bn, 96, W2p, bn, 96, l, a1, a2);
#pragma unroll
  for (int i = 0; i < 4; ++i) {
    const int row = m0 + w * 16 + ((l >> 4) << 2) + i;
#pragma unroll
    for (int s = 0; s < 2; ++s) {
      const int col = n0 + s * 16 + (l & 15);
      const float v1 = a1[s][i], v2 = a2[s][i];
      g_bf[(size_t)row * DFF_D + col] = f2b(v1 * sigf(v1) * v2);
    }
  }
}

// ---------------------------------------------------------------------------
// out = g_bf @ W3. Grid (4, 24).
// ---------------------------------------------------------------------------
__global__ __launch_bounds__(256) void k_out(const short* __restrict__ g_bf,
                                             const short* __restrict__ Bp,
                                             float* __restrict__ out) {
  WAVE_SETUP
  const int n0 = blockIdx.y * 32, bn = blockIdx.y * 2;
  const short* Arow = &g_bf[(size_t)rowA * DFF_D];
  f32x4 acc[2] = {(f32x4){0.f,0.f,0.f,0.f}, (f32x4){0.f,0.f,0.f,0.f}};
  mm_core<48, 2, false, DFF_D>(Arow, kg, Bp, bn, 48, nullptr, 0, 0, l, acc, nullptr);
#pragma unroll
  for (int i = 0; i < 4; ++i) {
    const int row = m0 + w * 16 + ((l >> 4) << 2) + i;
#pragma unroll
    for (int s = 0; s < 2; ++s) {
      const int col = n0 + s * 16 + (l & 15);
      out[(size_t)row * INP_D + col] = acc[s][i];
    }
  }
}

// ---------------------------------------------------------------------------
// Segmented scan — barrier-free wave-private version.
// Grid (24 e-tiles, 8 qc, 4 b), 64 threads (ONE wave). Lane = 16 e x 4 qsub.
// Each lane: 12 states; f/k/q per-lane float4 loads (16-lane HW broadcast);
// 2-token-deep register prefetch; cross-qsub reduce via 2x shfl_xor. No LDS,
// no __syncthreads -> per-step chain is compute + shfl only.
// ---------------------------------------------------------------------------
__global__ __launch_bounds__(64) void k_scan(const float* __restrict__ forget,
                                             const float* __restrict__ query,
                                             const float* __restrict__ keyv,
                                             const float* __restrict__ value,
                                             const float* __restrict__ is_first,
                                             const float* __restrict__ init_state,
                                             float* __restrict__ patt) {
  const int lane = threadIdx.x;          // 0..63
  const int et   = blockIdx.x;           // 0..23
  const int qc   = blockIdx.y;           // 0..7
  const int b    = blockIdx.z;           // 0..3
  const int e    = et * 16 + (lane & 15);
  const int qsub = lane >> 4;            // 0..3
  const int q0   = qc * 48 + qsub * 12;

  float s[12], ini[12];
#pragma unroll
  for (int j = 0; j < 12; ++j) {
    ini[j] = init_state[((size_t)b * Q_D + q0 + j) * E_D + e];
    s[j]   = ini[j];
  }

  // 2-deep register prefetch
  float4 f0[3], k0[3], qv0[3]; float v0, fi0;
  float4 f1[3], k1[3], qv1[3]; float v1, fi1;

#define SCAN_LD(tok, F, K, QV, V, FI, first)                                 \
  {                                                                          \
    const float* fp = &forget[(size_t)(tok) * Q_D + q0];                     \
    const float* kp = &keyv  [(size_t)(tok) * Q_D + q0];                     \
    const float* qp = &query [(size_t)(tok) * Q_D + q0];                     \
    F[0] = *(const float4*)&fp[0]; F[1] = *(const float4*)&fp[4]; F[2] = *(const float4*)&fp[8]; \
    K[0] = *(const float4*)&kp[0]; K[1] = *(const float4*)&kp[4]; K[2] = *(const float4*)&kp[8]; \
    QV[0] = *(const float4*)&qp[0]; QV[1] = *(const float4*)&qp[4]; QV[2] = *(const float4*)&qp[8]; \
    V = value[(size_t)(tok) * E_D + e];                                      \
    FI = (first) ? 0.0f : is_first[tok];                                     \
  }

  SCAN_LD(b, f0, k0, qv0, v0, fi0, true);
  SCAN_LD(B_DIM + b, f1, k1, qv1, v1, fi1, false);

  for (int t = 0; t < T_DIM; ++t) {
    const int tok = t * B_DIM + b;
    // current <- slot0
    float4 fc0 = f0[0], fc1 = f0[1], fc2 = f0[2];
    float4 kc0 = k0[0], kc1 = k0[1], kc2 = k0[2];
    float4 qc0 = qv0[0], qc1 = qv0[1], qc2 = qv0[2];
    const float vc = v0, fic = fi0;
    // rotate slot1 -> slot0
    f0[0] = f1[0]; f0[1] = f1[1]; f0[2] = f1[2];
    k0[0] = k1[0]; k0[1] = k1[1]; k0[2] = k1[2];
    qv0[0] = qv1[0]; qv0[1] = qv1[1]; qv0[2] = qv1[2];
    v0 = v1; fi0 = fi1;
    // prefetch t+2 -> slot1
    if (t + 2 < T_DIM) {
      SCAN_LD((t + 2) * B_DIM + b, f1, k1, qv1, v1, fi1, false);
    }

    if (fic > 0.5f) {
#pragma unroll
      for (int j = 0; j < 12; ++j) s[j] = ini[j];
    }
    float p = 0.0f;
    const float4 fr[3]  = {fc0, fc1, fc2};
    const float4 kr[3]  = {kc0, kc1, kc2};
    const float4 qr[3]  = {qc0, qc1, qc2};
#pragma unroll
    for (int r = 0; r < 3; ++r) {
#pragma unroll
      for (int j = 0; j < 4; ++j) {
        const int sj = r * 4 + j;
        s[sj] = fmaf((&fr[r].x)[j], s[sj], (&kr[r].x)[j] * vc);
        p     = fmaf((&qr[r].x)[j], s[sj], p);
      }
    }
    p += __shfl_xor(p, 16, 64);
    p += __shfl_xor(p, 32, 64);
    if (lane < 16)
      patt[((size_t)qc * NTOK + tok) * E_D + et * 16 + lane] = p;
  }
#undef SCAN_LD
}

// sum 8 scan slabs + RMS norm -> attn_bf (bf16)
__global__ __launch_bounds__(128) void ep_rms(const float* __restrict__ patt,
                                              const float* __restrict__ rms_w,
                                              short* __restrict__ attn_bf) {
  const int tok = blockIdx.x, tid = threadIdx.x;
  float x[3], ss = 0.0f;
#pragma unroll
  for (int i = 0; i < 3; ++i) {
    const int e = i * 128 + tid;
    float a = 0.0f;
#pragma unroll
    for (int qc = 0; qc < 8; ++qc) a += patt[((size_t)qc * NTOK + tok) * E_D + e];
    x[i] = a;
    ss = fmaf(a, a, ss);
  }
#pragma unroll
  for (int off = 32; off; off >>= 1) ss += __shfl_down(ss, off, 64);
  __shared__ float r[2];
  const int wid = tid >> 6, lane = tid & 63;
  if (lane == 0) r[wid] = ss;
  __syncthreads();
  ss = r[0] + r[1];
  const float sc = rsqrtf(ss * (1.0f / E_D) + 1e-6f);
#pragma unroll
  for (int i = 0; i < 3; ++i) {
    const int e = i * 128 + tid;
    attn_bf[(size_t)tok * E_D + e] = f2b(x[i] * sc * rms_w[e]);
  }
}

// LayerNorm over hpre -> h_bf (bf16)
__global__ __launch_bounds__(256) void ep_ln(const float* __restrict__ hpre,
                                             const float* __restrict__ ln_w,
                                             const float* __restrict__ ln_b,
                                             short* __restrict__ h_bf) {
  const int tok = blockIdx.x, tid = threadIdx.x;
  float x[3], s1 = 0.0f, s2 = 0.0f;
#pragma unroll
  for (int i = 0; i < 3; ++i) {
    x[i] = hpre[(size_t)tok * INP_D + i * 256 + tid];
    s1 += x[i];
    s2 = fmaf(x[i], x[i], s2);
  }
#pragma unroll
  for (int off = 32; off; off >>= 1) {
    s1 += __shfl_down(s1, off, 64);
    s2 += __shfl_down(s2, off, 64);
  }
  __shared__ float r1[4], r2[4];
  const int wid = tid >> 6, lane = tid & 63;
  if (lane == 0) { r1[wid] = s1; r2[wid] = s2; }
  __syncthreads();
  s1 = r1[0] + r1[1] + r1[2] + r1[3];
  s2 = r2[0] + r2[1] + r2[2] + r2[3];
  const float mean = s1 * (1.0f / INP_D);
  const float var  = s2 * (1.0f / INP_D) - mean * mean;
  const float sc   = rsqrtf(var + 1e-5f);
#pragma unroll
  for (int i = 0; i < 3; ++i) {
    const int c = i * 256 + tid;
    h_bf[(size_t)tok * INP_D + c] = f2b((x[i] - mean) * sc * ln_w[c] + ln_b[c]);
  }
}

extern "C" void kernel_launch(void* const* d_in, const int* in_sizes, int n_in,
                              void* d_out, int out_size, void* d_ws, size_t ws_size,
                              hipStream_t stream) {
  (void)in_sizes; (void)n_in; (void)out_size; (void)ws_size;
  const float* inp        = (const float*)d_in[0];
  const float* is_first   = (const float*)d_in[1];
  const float* drops      = (const float*)d_in[2];
  const float* init_inp   = (const float*)d_in[3];
  const float* init_state = (const float*)d_in[4];
  const float* mix_mu     = (const float*)d_in[5];
  const float* mix_W      = (const float*)d_in[6];
  const float* layer_W    = (const float*)d_in[7];
  const float* proj_W     = (const float*)d_in[8];
  const float* rms_w      = (const float*)d_in[9];
  const float* ln_w       = (const float*)d_in[10];
  const float* ln_b       = (const float*)d_in[11];
  const float* W1         = (const float*)d_in[12];
  const float* W2         = (const float*)d_in[13];
  const float* W3         = (const float*)d_in[14];
  float* out = (float*)d_out;
  float* ws  = (float*)d_ws;
  short* wsb = (short*)(ws + WS_BF);

  float* forget = ws + WS_FORGET;
  float* query  = ws + WS_QUERY;
  float* keyv   = ws + WS_KEYV;
  float* value  = ws + WS_VALUE;
  float* patt   = ws + WS_PATT;
  float* hpre   = ws + WS_HPRE;

  k_conv<<<2784, 256, 0, stream>>>(inp, is_first, init_inp, mix_mu,
                                   mix_W, layer_W, proj_W, W1, W2, W3, wsb);
  k_qkvfg<<<dim3(4, 48), 256, 0, stream>>>(wsb + PB_INP, wsb + PB_MIXED,
                                           wsb + PK_MIX, wsb + PK_LAYER, drops,
                                           forget, query, keyv, value);
  k_scan<<<dim3(24, 8, 4), 64, 0, stream>>>(forget, query, keyv, value,
                                            is_first, init_state, patt);
  ep_rms<<<NTOK, 128, 0, stream>>>(patt, rms_w, wsb + PB_ATTN);
  k_proj<<<dim3(4, 24), 256, 0, stream>>>(wsb + PB_ATTN, wsb + PK_PROJ, inp, hpre);
  ep_ln<<<NTOK, 256, 0, stream>>>(hpre, ln_w, ln_b, wsb + PB_H);
  k_ffn<<<dim3(4, 48), 256, 0, stream>>>(wsb + PB_H, wsb + PK_W1, wsb + PK_W2, wsb + PB_G);
  k_out<<<dim3(4, 24), 256, 0, stream>>>(wsb + PB_G, wsb + PK_W3, out);
}